// Round 21
// baseline (251.178 us; speedup 1.0000x reference)
//
#include <hip/hip_runtime.h>
#include <hip/hip_bf16.h>
#include <cstdint>
#include <cstddef>

// Problem constants
#define SS   2048
#define BB   2
#define HH   2048
#define NHEAD 16
#define HDIM 128
#define H3   6144
#define MROWS 4096   // S*B

typedef __attribute__((ext_vector_type(4))) float f32x4;
typedef __attribute__((ext_vector_type(8))) __bf16 bf16x8;
typedef __attribute__((ext_vector_type(8))) unsigned short us8;
typedef __attribute__((ext_vector_type(4))) unsigned short us4;

__device__ __forceinline__ unsigned short f2b_hw(float f) {
    return __builtin_bit_cast(unsigned short, (__bf16)f);
}

// raw v_exp_f32: D = 2^S0
__device__ __forceinline__ float exp2_fast(float x) {
    float r;
    asm("v_exp_f32 %0, %1" : "=v"(r) : "v"(x));
    return r;
}

__device__ __forceinline__ bf16x8 ld_b16x8(const unsigned short* p) {
    us8 u = *(const us8*)p;
    return __builtin_bit_cast(bf16x8, u);
}

__device__ __forceinline__ bf16x8 ld8_off(const unsigned short* base, int byteoff) {
    return __builtin_bit_cast(bf16x8, *(const us8*)((const char*)base + byteoff));
}

// LDS XOR swizzles (read side; staging uses pre-swizzled global source)
__device__ __forceinline__ int sw256(int b) { return b ^ (((b >> 8) & 7) << 4); }
__device__ __forceinline__ int sw128(int b) { return b ^ (((b >> 7) & 7) << 4); }

__device__ __forceinline__ void gload_lds16(const unsigned short* g, unsigned short* l) {
    __builtin_amdgcn_global_load_lds(
        (const __attribute__((address_space(1))) unsigned int*)g,
        (__attribute__((address_space(3))) unsigned int*)l, 16, 0, 0);
}

// ---------------------------------------------------------------------------
// fp32 -> bf16 conversion (memory-bound pre-pass)
// ---------------------------------------------------------------------------
__global__ __launch_bounds__(256) void cvt_f32_bf16(
    const float* __restrict__ in, unsigned short* __restrict__ out, int n4)
{
    const int stride = gridDim.x * blockDim.x;
    for (int i = blockIdx.x * blockDim.x + threadIdx.x; i < n4; i += stride) {
        const float4 v = ((const float4*)in)[i];
        us4 o = { f2b_hw(v.x), f2b_hw(v.y), f2b_hw(v.z), f2b_hw(v.w) };
        ((us4*)out)[i] = o;
    }
}

// ---------------------------------------------------------------------------
// V transpose pre-pass: mixed V sections -> vt[(bb*16+nh)*128 + d][s]
// ---------------------------------------------------------------------------
__global__ __launch_bounds__(256) void transpose_v(
    const unsigned short* __restrict__ mixed,
    unsigned short* __restrict__ vt)
{
    const int st = blockIdx.x;   // 0..31
    const int nh = blockIdx.y;
    const int bb = blockIdx.z;
    const int tid = threadIdx.x;
    __shared__ unsigned short T[64][136];
#pragma unroll
    for (int i = 0; i < 4; ++i) {
        const int c = i * 256 + tid;
        const int sl = c >> 4, d0 = (c & 15) << 3;
        const us8 v = *(const us8*)(mixed +
            ((size_t)(st * 64 + sl) * BB + bb) * H3 + nh * 384 + 256 + d0);
        *(us8*)(&T[sl][d0]) = v;
    }
    __syncthreads();
#pragma unroll
    for (int i = 0; i < 4; ++i) {
        const int c = i * 256 + tid;
        const int d = c >> 3, sl0 = (c & 7) << 3;
        us8 o;
#pragma unroll
        for (int j = 0; j < 8; ++j) o[j] = T[sl0 + j][d];
        *(us8*)(vt + ((size_t)(bb * NHEAD + nh) * HDIM + d) * SS + st * 64 + sl0) = o;
    }
}

// ---------------------------------------------------------------------------
// 128xBN 8-wave two-phase bf16 GEMM, R14-proven DOUBLE-buffered hazard
// structure (B(t+2) staged into the buffer B(t) vacated; counted vmcnt(NF)
// leaves exactly B(t+2)'s NF segments in flight, draining A(t+1)+B(t+1)).
// R21: BN=192 for QKV -> LDS = 32KB A-dbuf + 2x24KB B-dbuf = 80KB
// -> 2 blocks/CU (occupancy experiment with zero new sync semantics).
// Staging generalized to NF 8KB segments (512 thr x 16B each).
// For QKV (!F32OUT): Q columns (col%384 < 128) pre-scaled by log2e/sqrt(128).
// ---------------------------------------------------------------------------
template <int BN, bool F32OUT>
__global__ __launch_bounds__(512, 4) void gemm_8ph(
    const unsigned short* __restrict__ A,
    const unsigned short* __restrict__ Bw,
    const float* __restrict__ bias,
    void* __restrict__ Cout,
    int Nv, int Kv)
{
    extern __shared__ unsigned short smem[];
    constexpr int NF     = BN / 64;    // n-frags per wave = 8KB B segments
    constexpr int BELEMS = BN * 64;    // elems per B buffer

    const int tid  = threadIdx.x;
    const int lane = tid & 63;
    const int wave = tid >> 6;
    const int wm = wave >> 2, wn = wave & 3;
    const int bm = blockIdx.y, bn = blockIdx.x;

    const unsigned short* Ab = A  + (size_t)bm * 128 * Kv;
    const unsigned short* Bb = Bw + (size_t)bn * BN * Kv;

    // pre-swizzled source offsets: segment s covers bytes [(s*512+tid)*16 ..)
    int soffA[2], soffB[NF];
#pragma unroll
    for (int i = 0; i < 2; ++i) {
        const int p = (i * 512 + tid) * 16;
        const int l = p ^ (((p >> 7) & 7) << 4);
        soffA[i] = (l >> 7) * Kv + ((l & 127) >> 1);
    }
#pragma unroll
    for (int s = 0; s < NF; ++s) {
        const int p = (s * 512 + tid) * 16;
        const int l = p ^ (((p >> 7) & 7) << 4);
        soffB[s] = (l >> 7) * Kv + ((l & 127) >> 1);
    }

    f32x4 acc[4][NF];
#pragma unroll
    for (int m = 0; m < 4; ++m)
#pragma unroll
        for (int n = 0; n < NF; ++n) acc[m][n] = (f32x4){0.f, 0.f, 0.f, 0.f};

    const int frow = lane & 15;
    const int g16  = (lane >> 4) << 4;
    const int swx  = (frow & 7) << 4;
    const int kx0  = g16 ^ swx;
    const int kx1  = (64 + g16) ^ swx;
    const int aRow = (wm * 64 + frow) * 128;                // + m*2048 + aj
    const int bRow = 32768 + (wn * (BN / 4) + frow) * 128;  // + n*2048 + bj

    const int NT = Kv >> 6;

    // prologue: A(0)->A buf0; B(0)->B buf0; B(1)->B buf1
#pragma unroll
    for (int i = 0; i < 2; ++i)
        gload_lds16(Ab + soffA[i], smem + i * 4096 + tid * 8);
#pragma unroll
    for (int s = 0; s < NF; ++s)
        gload_lds16(Bb + soffB[s], smem + 16384 + s * 4096 + tid * 8);
#pragma unroll
    for (int s = 0; s < NF; ++s)
        gload_lds16(Bb + 64 + soffB[s], smem + 16384 + BELEMS + s * 4096 + tid * 8);
    if constexpr (NF == 3) { asm volatile("s_waitcnt vmcnt(3)" ::: "memory"); }
    else if constexpr (NF == 4) { asm volatile("s_waitcnt vmcnt(4)" ::: "memory"); }
    else { asm volatile("s_waitcnt vmcnt(6)" ::: "memory"); }
    __builtin_amdgcn_s_barrier();

    for (int t = 0; t < NT; ++t) {
        const int j  = t & 1;
        const int jn = j ^ 1;
        const int aj = j * 16384;         // A buf byte base
        const int bj = j * (BN * 128);    // B buf byte add
        const int cA = ((t + 1 < NT) ? (t + 1) : (NT - 1)) * 64;
        const int cB = ((t + 2 < NT) ? (t + 2) : (NT - 1)) * 64;

        bf16x8 bbf[NF][2];

        // ---- phase 0: all B frags + A m0,m1; stage A(t+1) -> A buf jn
        {
            bf16x8 a00 = ld8_off(smem, aj + aRow + 0 * 2048 + kx0);
            bf16x8 a01 = ld8_off(smem, aj + aRow + 0 * 2048 + kx1);
            bf16x8 a10 = ld8_off(smem, aj + aRow + 1 * 2048 + kx0);
            bf16x8 a11 = ld8_off(smem, aj + aRow + 1 * 2048 + kx1);
#pragma unroll
            for (int n = 0; n < NF; ++n) {
                bbf[n][0] = ld8_off(smem, bj + bRow + n * 2048 + kx0);
                bbf[n][1] = ld8_off(smem, bj + bRow + n * 2048 + kx1);
            }
#pragma unroll
            for (int i = 0; i < 2; ++i)
                gload_lds16(Ab + cA + soffA[i], smem + jn * 8192 + i * 4096 + tid * 8);
            __builtin_amdgcn_s_barrier();
            __builtin_amdgcn_s_setprio(1);
#pragma unroll
            for (int n = 0; n < NF; ++n) {
                acc[0][n] = __builtin_amdgcn_mfma_f32_16x16x32_bf16(a00, bbf[n][0], acc[0][n], 0, 0, 0);
                acc[0][n] = __builtin_amdgcn_mfma_f32_16x16x32_bf16(a01, bbf[n][1], acc[0][n], 0, 0, 0);
                acc[1][n] = __builtin_amdgcn_mfma_f32_16x16x32_bf16(a10, bbf[n][0], acc[1][n], 0, 0, 0);
                acc[1][n] = __builtin_amdgcn_mfma_f32_16x16x32_bf16(a11, bbf[n][1], acc[1][n], 0, 0, 0);
            }
            __builtin_amdgcn_s_setprio(0);
        }
        // ---- phase 1: A m2,m3; stage B(t+2) -> B buf j (vacated); vmcnt(NF)
        {
            bf16x8 a00 = ld8_off(smem, aj + aRow + 2 * 2048 + kx0);
            bf16x8 a01 = ld8_off(smem, aj + aRow + 2 * 2048 + kx1);
            bf16x8 a10 = ld8_off(smem, aj + aRow + 3 * 2048 + kx0);
            bf16x8 a11 = ld8_off(smem, aj + aRow + 3 * 2048 + kx1);
#pragma unroll
            for (int s = 0; s < NF; ++s)
                gload_lds16(Bb + cB + soffB[s],
                            smem + 16384 + j * BELEMS + s * 4096 + tid * 8);
            __builtin_amdgcn_s_barrier();
            __builtin_amdgcn_s_setprio(1);
#pragma unroll
            for (int n = 0; n < NF; ++n) {
                acc[2][n] = __builtin_amdgcn_mfma_f32_16x16x32_bf16(a00, bbf[n][0], acc[2][n], 0, 0, 0);
                acc[2][n] = __builtin_amdgcn_mfma_f32_16x16x32_bf16(a01, bbf[n][1], acc[2][n], 0, 0, 0);
                acc[3][n] = __builtin_amdgcn_mfma_f32_16x16x32_bf16(a10, bbf[n][0], acc[3][n], 0, 0, 0);
                acc[3][n] = __builtin_amdgcn_mfma_f32_16x16x32_bf16(a11, bbf[n][1], acc[3][n], 0, 0, 0);
            }
            __builtin_amdgcn_s_setprio(0);
            if constexpr (NF == 3) { asm volatile("s_waitcnt vmcnt(3)" ::: "memory"); }
            else if constexpr (NF == 4) { asm volatile("s_waitcnt vmcnt(4)" ::: "memory"); }
            else { asm volatile("s_waitcnt vmcnt(6)" ::: "memory"); }
        }
    }

    // epilogue
    const int r0 = (lane >> 4) << 2;
#pragma unroll
    for (int m = 0; m < 4; ++m) {
        const int row = bm * 128 + wm * 64 + m * 16 + r0;
#pragma unroll
        for (int n = 0; n < NF; ++n) {
            const int col = bn * BN + wn * (BN / 4) + n * 16 + frow;
            const float bv = bias[col];
            float scale = 1.0f;
            if constexpr (!F32OUT) {
                // QKV: fold softmax 1/sqrt(128) AND log2e into Q columns
                if ((col % 384) < 128)
                    scale = (float)(0.08838834764831843 * 1.4426950408889634);
            }
#pragma unroll
            for (int r = 0; r < 4; ++r) {
                const float o = (acc[m][n][r] + bv) * scale;
                if (F32OUT) ((float*)Cout)[(size_t)(row + r) * Nv + col] = o;
                else        ((unsigned short*)Cout)[(size_t)(row + r) * Nv + col] = f2b_hw(o);
            }
        }
    }
}

// ---------------------------------------------------------------------------
// Flash attention (causal), R19 structure (passed, 236.1us): KVBLK=64,
// single-buffered K/V 2-barrier schedule (syncthreads drains), 40KB LDS,
// paired q-tiles, XCD remap, exp2-domain scores, defer-max, l-via-ones-MFMA,
// HW bf16 cvt, diag-only mask.
// ---------------------------------------------------------------------------
__global__ __launch_bounds__(256) void attn_kernel(
    const unsigned short* __restrict__ mixed,
    const unsigned short* __restrict__ vt,
    unsigned short* __restrict__ context)
{
    // XCD-locality remap: id = c + 8*(pair + 16*grp), nhbb = c + 8*grp
    const int id   = blockIdx.x;       // 0..511
    const int c    = id & 7;
    const int k    = id >> 3;
    const int pair = k & 15;
    const int nhbb = c + 8 * (k >> 4);
    const int nh   = nhbb >> 1;
    const int bb   = nhbb & 1;

    const int tid  = threadIdx.x;
    const int lane = tid & 63;
    const int wave = tid >> 6;

    __shared__ __align__(1024) unsigned short smem[8192 + 8192 + 4096]; // 40KB

    const int frow = lane & 15;
    const int g16  = (lane >> 4) << 4;
    const int r0   = (lane >> 4) << 2;
    const int kb8  = (lane >> 4) << 3;

    int koff[4], voff[4];
#pragma unroll
    for (int i = 0; i < 4; ++i) {
        const int p0 = (i * 256 + tid) * 16;
        const int lK = p0 ^ (((p0 >> 8) & 7) << 4);
        koff[i] = (lK >> 8) * (BB * H3) + ((lK & 255) >> 1);
        const int lV = p0 ^ (((p0 >> 7) & 7) << 4);
        voff[i] = (lV >> 7) * SS + ((lV & 127) >> 1);
    }

    const unsigned short* kg = mixed + (size_t)bb * H3 + nh * 384 + 128;
    const unsigned short* vg = vt + (size_t)(bb * NHEAD + nh) * HDIM * SS;

    unsigned short* Ksm = smem;
    unsigned short* Vsm = smem + 8192;
    char* Pb = (char*)(smem + 16384) + wave * 2048;

    // all-ones B fragment for the l-accumulator MFMA
    bf16x8 ones;
#pragma unroll
    for (int j = 0; j < 8; ++j) ones[j] = (__bf16)1.0f;

    for (int half = 0; half < 2; ++half) {
        const int qt = half ? (31 - pair) : pair;
        const int q0 = qt * 64 + wave * 16;

        bf16x8 qf[4];
        {
            const unsigned short* qptr =
                mixed + ((size_t)(q0 + frow) * BB + bb) * H3 + nh * 384;
#pragma unroll
            for (int kk = 0; kk < 4; ++kk)
                qf[kk] = ld_b16x8(qptr + kk * 32 + kb8);
        }

        f32x4 Oacc[8];
#pragma unroll
        for (int ct = 0; ct < 8; ++ct) Oacc[ct] = (f32x4){0.f, 0.f, 0.f, 0.f};
        f32x4 lacc = (f32x4){0.f, 0.f, 0.f, 0.f};
        float m_r[4] = {-1e30f, -1e30f, -1e30f, -1e30f};

        // prologue: stage K0 + V0
#pragma unroll
        for (int i = 0; i < 4; ++i) {
            gload_lds16(kg + koff[i], Ksm + i * 2048 + tid * 8);
            gload_lds16(vg + voff[i], Vsm + i * 2048 + tid * 8);
        }
        __syncthreads();

        for (int kt = 0; kt <= qt; ++kt) {
            // QK^T (scores arrive pre-scaled, exp2 domain)
            f32x4 sc4[4];
#pragma unroll
            for (int t = 0; t < 4; ++t) {
                f32x4 s = (f32x4){0.f, 0.f, 0.f, 0.f};
#pragma unroll
                for (int kk = 0; kk < 4; ++kk) {
                    bf16x8 kf = ld8_off(Ksm, sw256((t * 16 + frow) * 256 + kk * 64 + g16));
                    s = __builtin_amdgcn_mfma_f32_16x16x32_bf16(qf[kk], kf, s, 0, 0, 0);
                }
                sc4[t] = s;
            }

            __syncthreads();   // barrier A: all K reads done; V(kt) landed
            if (kt < qt) {
                const unsigned short* kt_g = kg + (size_t)(kt + 1) * 64 * (BB * H3);
#pragma unroll
                for (int i = 0; i < 4; ++i)
                    gload_lds16(kt_g + koff[i], Ksm + i * 2048 + tid * 8);
            }

            // causal mask: only the diagonal tile can mask
            if (kt == qt) {
#pragma unroll
                for (int t = 0; t < 4; ++t) {
                    const int kcol = qt * 64 + t * 16 + frow;
#pragma unroll
                    for (int r = 0; r < 4; ++r)
                        if (kcol > q0 + r0 + r) sc4[t][r] = -1e30f;
                }
            }

            // defer-max gate on per-thread partial max
            float pmax[4];
#pragma unroll
            for (int r = 0; r < 4; ++r)
                pmax[r] = fmaxf(fmaxf(sc4[0][r], sc4[1][r]), fmaxf(sc4[2][r], sc4[3][r]));
            bool need = false;
#pragma unroll
            for (int r = 0; r < 4; ++r) need = need || (pmax[r] > m_r[r] + 11.5f);
            if (__any(need)) {
                float tmax[4];
#pragma unroll
                for (int r = 0; r < 4; ++r) {
                    tmax[r] = pmax[r];
                    tmax[r] = fmaxf(tmax[r], __shfl_xor(tmax[r], 1, 64));
                    tmax[r] = fmaxf(tmax[r], __shfl_xor(tmax[r], 2, 64));
                    tmax[r] = fmaxf(tmax[r], __shfl_xor(tmax[r], 4, 64));
                    tmax[r] = fmaxf(tmax[r], __shfl_xor(tmax[r], 8, 64));
                }
                float a_r[4];
#pragma unroll
                for (int r = 0; r < 4; ++r) {
                    const float mnew = fmaxf(m_r[r], tmax[r]);
                    a_r[r] = exp2_fast(m_r[r] - mnew);
                    m_r[r] = mnew;
                    lacc[r] *= a_r[r];
                }
#pragma unroll
                for (int ct = 0; ct < 8; ++ct)
#pragma unroll
                    for (int r = 0; r < 4; ++r) Oacc[ct][r] *= a_r[r];
            }

            // P = exp2(S - m) -> LDS (per-wave, swizzled, HW cvt)
#pragma unroll
            for (int t = 0; t < 4; ++t)
#pragma unroll
                for (int r = 0; r < 4; ++r)
                    *(unsigned short*)(Pb + sw128((r0 + r) * 128 + (t * 16 + frow) * 2)) =
                        f2b_hw(exp2_fast(sc4[t][r] - m_r[r]));

            // PV + l-accumulate (ones column)
#pragma unroll
            for (int ks = 0; ks < 2; ++ks) {
                bf16x8 pf = ld8_off((const unsigned short*)Pb, sw128(frow * 128 + ks * 64 + g16));
                lacc = __builtin_amdgcn_mfma_f32_16x16x32_bf16(pf, ones, lacc, 0, 0, 0);
#pragma unroll
                for (int ct = 0; ct < 8; ++ct) {
                    bf16x8 vf = ld8_off(Vsm, sw128((ct * 16 + frow) * 128 + ks * 64 + g16));
                    Oacc[ct] = __builtin_amdgcn_mfma_f32_16x16x32_bf16(pf, vf, Oacc[ct], 0, 0, 0);
                }
            }

            __syncthreads();   // barrier B: all V reads done; K(kt+1) landed
            if (kt < qt) {
                const unsigned short* vt_g = vg + (kt + 1) * 64;
#pragma unroll
                for (int i = 0; i < 4; ++i)
                    gload_lds16(vt_g + voff[i], Vsm + i * 2048 + tid * 8);
            }
        }

        // epilogue: rcp multiply (l >= 1: diagonal contributes exp2(0))
        float rl[4];
#pragma unroll
        for (int r = 0; r < 4; ++r) rl[r] = __builtin_amdgcn_rcpf(lacc[r]);
#pragma unroll
        for (int ct = 0; ct < 8; ++ct) {
            const int d = ct * 16 + frow;
#pragma unroll
            for (int r = 0; r < 4; ++r) {
                const size_t row = (size_t)(q0 + r0 + r) * BB + bb;
                context[row * HH + nh * 128 + d] = f2b_hw(Oacc[ct][r] * rl[r]);
            }
        }
    }
}

extern "C" void kernel_launch(void* const* d_in, const int* in_sizes, int n_in,
                              void* d_out, int out_size, void* d_ws, size_t ws_size,
                              hipStream_t stream) {
    const float* hidden  = (const float*)d_in[0];
    // d_in[1] = attention_mask: deterministically causal (triu k=1) -> applied analytically
    const float* w_qkv   = (const float*)d_in[2];
    const float* b_qkv   = (const float*)d_in[3];
    const float* w_dense = (const float*)d_in[4];
    const float* b_dense = (const float*)d_in[5];
    float* out = (float*)d_out;

    // ws layout (bf16 elements), 96MB total:
    //  [mixed 48MB][hb 16MB -> context after GEMM1][wq 24MB -> vt after GEMM1][wd 8MB]
    unsigned short* mixed = (unsigned short*)d_ws;
    unsigned short* hb    = mixed + (size_t)MROWS * H3;
    unsigned short* wq    = hb + (size_t)MROWS * HH;
    unsigned short* wd    = wq + (size_t)H3 * HH;
    unsigned short* context = hb;   // alias: hb dead after GEMM1
    unsigned short* vtg     = wq;   // alias: wq dead after GEMM1 (16MB <= 24MB)

    dim3 blk(256);
    // fp32 -> bf16 pre-passes (memory-bound)
    cvt_f32_bf16<<<2048, blk, 0, stream>>>(hidden, hb, (MROWS * HH) / 4);
    cvt_f32_bf16<<<2048, blk, 0, stream>>>(w_qkv, wq, (H3 * HH) / 4);
    cvt_f32_bf16<<<1024, blk, 0, stream>>>(w_dense, wd, (HH * HH) / 4);

    // QKV projection: [4096,2048] x [6144,2048]^T -> mixed bf16 (Q pre-scaled)
    // BN=192, 80KB LDS -> 2 blocks/CU; grid 32x32 = 1024 = 2 resident rounds
    hipFuncSetAttribute(reinterpret_cast<const void*>(gemm_8ph<192, false>),
                        hipFuncAttributeMaxDynamicSharedMemorySize, 81920);
    gemm_8ph<192, false><<<dim3(H3 / 192, MROWS / 128), dim3(512), 81920, stream>>>(
        hb, wq, b_qkv, mixed, H3, HH);
    // V transpose pre-pass: mixed -> vtg [b*head][d][s]
    transpose_v<<<dim3(32, NHEAD, BB), blk, 0, stream>>>(mixed, vtg);
    // causal flash attention -> context bf16 (512 blocks, XCD remap, paired)
    attn_kernel<<<dim3(512), blk, 0, stream>>>(mixed, vtg, context);
    // dense projection: [4096,2048] x [2048,2048]^T -> out fp32
    // BN=256, 96KB LDS (identical behavior to R19 dense)
    hipFuncSetAttribute(reinterpret_cast<const void*>(gemm_8ph<256, true>),
                        hipFuncAttributeMaxDynamicSharedMemorySize, 98304);
    gemm_8ph<256, true><<<dim3(HH / 256, MROWS / 128), dim3(512), 98304, stream>>>(
        context, wd, b_dense, out, HH, HH);
}

// Round 22
// 235.484 us; speedup vs baseline: 1.0666x; 1.0666x over previous
//
#include <hip/hip_runtime.h>
#include <hip/hip_bf16.h>
#include <cstdint>
#include <cstddef>

// Problem constants
#define SS   2048
#define BB   2
#define HH   2048
#define NHEAD 16
#define HDIM 128
#define H3   6144
#define MROWS 4096   // S*B

typedef __attribute__((ext_vector_type(4))) float f32x4;
typedef __attribute__((ext_vector_type(8))) __bf16 bf16x8;
typedef __attribute__((ext_vector_type(8))) unsigned short us8;
typedef __attribute__((ext_vector_type(4))) unsigned short us4;

__device__ __forceinline__ unsigned short f2b_hw(float f) {
    return __builtin_bit_cast(unsigned short, (__bf16)f);
}

// raw v_exp_f32: D = 2^S0
__device__ __forceinline__ float exp2_fast(float x) {
    float r;
    asm("v_exp_f32 %0, %1" : "=v"(r) : "v"(x));
    return r;
}

__device__ __forceinline__ bf16x8 ld_b16x8(const unsigned short* p) {
    us8 u = *(const us8*)p;
    return __builtin_bit_cast(bf16x8, u);
}

__device__ __forceinline__ bf16x8 ld8_off(const unsigned short* base, int byteoff) {
    return __builtin_bit_cast(bf16x8, *(const us8*)((const char*)base + byteoff));
}

// LDS XOR swizzles (read side; staging uses pre-swizzled global source)
__device__ __forceinline__ int sw256(int b) { return b ^ (((b >> 8) & 7) << 4); }
__device__ __forceinline__ int sw128(int b) { return b ^ (((b >> 7) & 7) << 4); }

__device__ __forceinline__ void gload_lds16(const unsigned short* g, unsigned short* l) {
    __builtin_amdgcn_global_load_lds(
        (const __attribute__((address_space(1))) unsigned int*)g,
        (__attribute__((address_space(3))) unsigned int*)l, 16, 0, 0);
}

// ---------------------------------------------------------------------------
// fp32 -> bf16 conversion (memory-bound pre-pass)
// ---------------------------------------------------------------------------
__global__ __launch_bounds__(256) void cvt_f32_bf16(
    const float* __restrict__ in, unsigned short* __restrict__ out, int n4)
{
    const int stride = gridDim.x * blockDim.x;
    for (int i = blockIdx.x * blockDim.x + threadIdx.x; i < n4; i += stride) {
        const float4 v = ((const float4*)in)[i];
        us4 o = { f2b_hw(v.x), f2b_hw(v.y), f2b_hw(v.z), f2b_hw(v.w) };
        ((us4*)out)[i] = o;
    }
}

// ---------------------------------------------------------------------------
// V transpose pre-pass: mixed V sections -> vt[(bb*16+nh)*128 + d][s]
// ---------------------------------------------------------------------------
__global__ __launch_bounds__(256) void transpose_v(
    const unsigned short* __restrict__ mixed,
    unsigned short* __restrict__ vt)
{
    const int st = blockIdx.x;   // 0..31
    const int nh = blockIdx.y;
    const int bb = blockIdx.z;
    const int tid = threadIdx.x;
    __shared__ unsigned short T[64][136];
#pragma unroll
    for (int i = 0; i < 4; ++i) {
        const int c = i * 256 + tid;
        const int sl = c >> 4, d0 = (c & 15) << 3;
        const us8 v = *(const us8*)(mixed +
            ((size_t)(st * 64 + sl) * BB + bb) * H3 + nh * 384 + 256 + d0);
        *(us8*)(&T[sl][d0]) = v;
    }
    __syncthreads();
#pragma unroll
    for (int i = 0; i < 4; ++i) {
        const int c = i * 256 + tid;
        const int d = c >> 3, sl0 = (c & 7) << 3;
        us8 o;
#pragma unroll
        for (int j = 0; j < 8; ++j) o[j] = T[sl0 + j][d];
        *(us8*)(vt + ((size_t)(bb * NHEAD + nh) * HDIM + d) * SS + st * 64 + sl0) = o;
    }
}

// ---------------------------------------------------------------------------
// 128xBN 8-wave two-phase bf16 GEMM, R14-proven double-buffered hazard
// structure. MINW = min waves/EU (launch_bounds): QKV uses <192, MINW=4>
// (80KB LDS -> 2 blocks/CU; R21-measured 95us, MfmaUtil 50%, occ 35%);
// dense uses <256, MINW=2> (96KB LDS, R19-proven ~33us — MINW=4 spilled
// NF=4's 64-reg accumulator and was a 1.8%-util disaster in R21).
// For QKV (!F32OUT): Q columns (col%384 < 128) pre-scaled by log2e/sqrt(128).
// ---------------------------------------------------------------------------
template <int BN, bool F32OUT, int MINW>
__global__ __launch_bounds__(512, MINW) void gemm_8ph(
    const unsigned short* __restrict__ A,
    const unsigned short* __restrict__ Bw,
    const float* __restrict__ bias,
    void* __restrict__ Cout,
    int Nv, int Kv)
{
    extern __shared__ unsigned short smem[];
    constexpr int NF     = BN / 64;    // n-frags per wave = 8KB B segments
    constexpr int BELEMS = BN * 64;    // elems per B buffer

    const int tid  = threadIdx.x;
    const int lane = tid & 63;
    const int wave = tid >> 6;
    const int wm = wave >> 2, wn = wave & 3;
    const int bm = blockIdx.y, bn = blockIdx.x;

    const unsigned short* Ab = A  + (size_t)bm * 128 * Kv;
    const unsigned short* Bb = Bw + (size_t)bn * BN * Kv;

    // pre-swizzled source offsets: segment s covers bytes [(s*512+tid)*16 ..)
    int soffA[2], soffB[NF];
#pragma unroll
    for (int i = 0; i < 2; ++i) {
        const int p = (i * 512 + tid) * 16;
        const int l = p ^ (((p >> 7) & 7) << 4);
        soffA[i] = (l >> 7) * Kv + ((l & 127) >> 1);
    }
#pragma unroll
    for (int s = 0; s < NF; ++s) {
        const int p = (s * 512 + tid) * 16;
        const int l = p ^ (((p >> 7) & 7) << 4);
        soffB[s] = (l >> 7) * Kv + ((l & 127) >> 1);
    }

    f32x4 acc[4][NF];
#pragma unroll
    for (int m = 0; m < 4; ++m)
#pragma unroll
        for (int n = 0; n < NF; ++n) acc[m][n] = (f32x4){0.f, 0.f, 0.f, 0.f};

    const int frow = lane & 15;
    const int g16  = (lane >> 4) << 4;
    const int swx  = (frow & 7) << 4;
    const int kx0  = g16 ^ swx;
    const int kx1  = (64 + g16) ^ swx;
    const int aRow = (wm * 64 + frow) * 128;                // + m*2048 + aj
    const int bRow = 32768 + (wn * (BN / 4) + frow) * 128;  // + n*2048 + bj

    const int NT = Kv >> 6;

    // prologue: A(0)->A buf0; B(0)->B buf0; B(1)->B buf1
#pragma unroll
    for (int i = 0; i < 2; ++i)
        gload_lds16(Ab + soffA[i], smem + i * 4096 + tid * 8);
#pragma unroll
    for (int s = 0; s < NF; ++s)
        gload_lds16(Bb + soffB[s], smem + 16384 + s * 4096 + tid * 8);
#pragma unroll
    for (int s = 0; s < NF; ++s)
        gload_lds16(Bb + 64 + soffB[s], smem + 16384 + BELEMS + s * 4096 + tid * 8);
    if constexpr (NF == 3) { asm volatile("s_waitcnt vmcnt(3)" ::: "memory"); }
    else if constexpr (NF == 4) { asm volatile("s_waitcnt vmcnt(4)" ::: "memory"); }
    else { asm volatile("s_waitcnt vmcnt(6)" ::: "memory"); }
    __builtin_amdgcn_s_barrier();

    for (int t = 0; t < NT; ++t) {
        const int j  = t & 1;
        const int jn = j ^ 1;
        const int aj = j * 16384;         // A buf byte base
        const int bj = j * (BN * 128);    // B buf byte add
        const int cA = ((t + 1 < NT) ? (t + 1) : (NT - 1)) * 64;
        const int cB = ((t + 2 < NT) ? (t + 2) : (NT - 1)) * 64;

        bf16x8 bbf[NF][2];

        // ---- phase 0: all B frags + A m0,m1; stage A(t+1) -> A buf jn
        {
            bf16x8 a00 = ld8_off(smem, aj + aRow + 0 * 2048 + kx0);
            bf16x8 a01 = ld8_off(smem, aj + aRow + 0 * 2048 + kx1);
            bf16x8 a10 = ld8_off(smem, aj + aRow + 1 * 2048 + kx0);
            bf16x8 a11 = ld8_off(smem, aj + aRow + 1 * 2048 + kx1);
#pragma unroll
            for (int n = 0; n < NF; ++n) {
                bbf[n][0] = ld8_off(smem, bj + bRow + n * 2048 + kx0);
                bbf[n][1] = ld8_off(smem, bj + bRow + n * 2048 + kx1);
            }
#pragma unroll
            for (int i = 0; i < 2; ++i)
                gload_lds16(Ab + cA + soffA[i], smem + jn * 8192 + i * 4096 + tid * 8);
            __builtin_amdgcn_s_barrier();
            __builtin_amdgcn_s_setprio(1);
#pragma unroll
            for (int n = 0; n < NF; ++n) {
                acc[0][n] = __builtin_amdgcn_mfma_f32_16x16x32_bf16(a00, bbf[n][0], acc[0][n], 0, 0, 0);
                acc[0][n] = __builtin_amdgcn_mfma_f32_16x16x32_bf16(a01, bbf[n][1], acc[0][n], 0, 0, 0);
                acc[1][n] = __builtin_amdgcn_mfma_f32_16x16x32_bf16(a10, bbf[n][0], acc[1][n], 0, 0, 0);
                acc[1][n] = __builtin_amdgcn_mfma_f32_16x16x32_bf16(a11, bbf[n][1], acc[1][n], 0, 0, 0);
            }
            __builtin_amdgcn_s_setprio(0);
        }
        // ---- phase 1: A m2,m3; stage B(t+2) -> B buf j (vacated); vmcnt(NF)
        {
            bf16x8 a00 = ld8_off(smem, aj + aRow + 2 * 2048 + kx0);
            bf16x8 a01 = ld8_off(smem, aj + aRow + 2 * 2048 + kx1);
            bf16x8 a10 = ld8_off(smem, aj + aRow + 3 * 2048 + kx0);
            bf16x8 a11 = ld8_off(smem, aj + aRow + 3 * 2048 + kx1);
#pragma unroll
            for (int s = 0; s < NF; ++s)
                gload_lds16(Bb + cB + soffB[s],
                            smem + 16384 + j * BELEMS + s * 4096 + tid * 8);
            __builtin_amdgcn_s_barrier();
            __builtin_amdgcn_s_setprio(1);
#pragma unroll
            for (int n = 0; n < NF; ++n) {
                acc[2][n] = __builtin_amdgcn_mfma_f32_16x16x32_bf16(a00, bbf[n][0], acc[2][n], 0, 0, 0);
                acc[2][n] = __builtin_amdgcn_mfma_f32_16x16x32_bf16(a01, bbf[n][1], acc[2][n], 0, 0, 0);
                acc[3][n] = __builtin_amdgcn_mfma_f32_16x16x32_bf16(a10, bbf[n][0], acc[3][n], 0, 0, 0);
                acc[3][n] = __builtin_amdgcn_mfma_f32_16x16x32_bf16(a11, bbf[n][1], acc[3][n], 0, 0, 0);
            }
            __builtin_amdgcn_s_setprio(0);
            if constexpr (NF == 3) { asm volatile("s_waitcnt vmcnt(3)" ::: "memory"); }
            else if constexpr (NF == 4) { asm volatile("s_waitcnt vmcnt(4)" ::: "memory"); }
            else { asm volatile("s_waitcnt vmcnt(6)" ::: "memory"); }
        }
    }

    // epilogue
    const int r0 = (lane >> 4) << 2;
#pragma unroll
    for (int m = 0; m < 4; ++m) {
        const int row = bm * 128 + wm * 64 + m * 16 + r0;
#pragma unroll
        for (int n = 0; n < NF; ++n) {
            const int col = bn * BN + wn * (BN / 4) + n * 16 + frow;
            const float bv = bias[col];
            float scale = 1.0f;
            if constexpr (!F32OUT) {
                // QKV: fold softmax 1/sqrt(128) AND log2e into Q columns
                if ((col % 384) < 128)
                    scale = (float)(0.08838834764831843 * 1.4426950408889634);
            }
#pragma unroll
            for (int r = 0; r < 4; ++r) {
                const float o = (acc[m][n][r] + bv) * scale;
                if (F32OUT) ((float*)Cout)[(size_t)(row + r) * Nv + col] = o;
                else        ((unsigned short*)Cout)[(size_t)(row + r) * Nv + col] = f2b_hw(o);
            }
        }
    }
}

// ---------------------------------------------------------------------------
// Flash attention (causal), R19 structure (passed, 236.1us): KVBLK=64,
// single-buffered K/V 2-barrier schedule (syncthreads drains), 40KB LDS,
// paired q-tiles, XCD remap, exp2-domain scores, defer-max, l-via-ones-MFMA,
// HW bf16 cvt, diag-only mask.
// ---------------------------------------------------------------------------
__global__ __launch_bounds__(256) void attn_kernel(
    const unsigned short* __restrict__ mixed,
    const unsigned short* __restrict__ vt,
    unsigned short* __restrict__ context)
{
    // XCD-locality remap: id = c + 8*(pair + 16*grp), nhbb = c + 8*grp
    const int id   = blockIdx.x;       // 0..511
    const int c    = id & 7;
    const int k    = id >> 3;
    const int pair = k & 15;
    const int nhbb = c + 8 * (k >> 4);
    const int nh   = nhbb >> 1;
    const int bb   = nhbb & 1;

    const int tid  = threadIdx.x;
    const int lane = tid & 63;
    const int wave = tid >> 6;

    __shared__ __align__(1024) unsigned short smem[8192 + 8192 + 4096]; // 40KB

    const int frow = lane & 15;
    const int g16  = (lane >> 4) << 4;
    const int r0   = (lane >> 4) << 2;
    const int kb8  = (lane >> 4) << 3;

    int koff[4], voff[4];
#pragma unroll
    for (int i = 0; i < 4; ++i) {
        const int p0 = (i * 256 + tid) * 16;
        const int lK = p0 ^ (((p0 >> 8) & 7) << 4);
        koff[i] = (lK >> 8) * (BB * H3) + ((lK & 255) >> 1);
        const int lV = p0 ^ (((p0 >> 7) & 7) << 4);
        voff[i] = (lV >> 7) * SS + ((lV & 127) >> 1);
    }

    const unsigned short* kg = mixed + (size_t)bb * H3 + nh * 384 + 128;
    const unsigned short* vg = vt + (size_t)(bb * NHEAD + nh) * HDIM * SS;

    unsigned short* Ksm = smem;
    unsigned short* Vsm = smem + 8192;
    char* Pb = (char*)(smem + 16384) + wave * 2048;

    // all-ones B fragment for the l-accumulator MFMA
    bf16x8 ones;
#pragma unroll
    for (int j = 0; j < 8; ++j) ones[j] = (__bf16)1.0f;

    for (int half = 0; half < 2; ++half) {
        const int qt = half ? (31 - pair) : pair;
        const int q0 = qt * 64 + wave * 16;

        bf16x8 qf[4];
        {
            const unsigned short* qptr =
                mixed + ((size_t)(q0 + frow) * BB + bb) * H3 + nh * 384;
#pragma unroll
            for (int kk = 0; kk < 4; ++kk)
                qf[kk] = ld_b16x8(qptr + kk * 32 + kb8);
        }

        f32x4 Oacc[8];
#pragma unroll
        for (int ct = 0; ct < 8; ++ct) Oacc[ct] = (f32x4){0.f, 0.f, 0.f, 0.f};
        f32x4 lacc = (f32x4){0.f, 0.f, 0.f, 0.f};
        float m_r[4] = {-1e30f, -1e30f, -1e30f, -1e30f};

        // prologue: stage K0 + V0
#pragma unroll
        for (int i = 0; i < 4; ++i) {
            gload_lds16(kg + koff[i], Ksm + i * 2048 + tid * 8);
            gload_lds16(vg + voff[i], Vsm + i * 2048 + tid * 8);
        }
        __syncthreads();

        for (int kt = 0; kt <= qt; ++kt) {
            // QK^T (scores arrive pre-scaled, exp2 domain)
            f32x4 sc4[4];
#pragma unroll
            for (int t = 0; t < 4; ++t) {
                f32x4 s = (f32x4){0.f, 0.f, 0.f, 0.f};
#pragma unroll
                for (int kk = 0; kk < 4; ++kk) {
                    bf16x8 kf = ld8_off(Ksm, sw256((t * 16 + frow) * 256 + kk * 64 + g16));
                    s = __builtin_amdgcn_mfma_f32_16x16x32_bf16(qf[kk], kf, s, 0, 0, 0);
                }
                sc4[t] = s;
            }

            __syncthreads();   // barrier A: all K reads done; V(kt) landed
            if (kt < qt) {
                const unsigned short* kt_g = kg + (size_t)(kt + 1) * 64 * (BB * H3);
#pragma unroll
                for (int i = 0; i < 4; ++i)
                    gload_lds16(kt_g + koff[i], Ksm + i * 2048 + tid * 8);
            }

            // causal mask: only the diagonal tile can mask
            if (kt == qt) {
#pragma unroll
                for (int t = 0; t < 4; ++t) {
                    const int kcol = qt * 64 + t * 16 + frow;
#pragma unroll
                    for (int r = 0; r < 4; ++r)
                        if (kcol > q0 + r0 + r) sc4[t][r] = -1e30f;
                }
            }

            // defer-max gate on per-thread partial max
            float pmax[4];
#pragma unroll
            for (int r = 0; r < 4; ++r)
                pmax[r] = fmaxf(fmaxf(sc4[0][r], sc4[1][r]), fmaxf(sc4[2][r], sc4[3][r]));
            bool need = false;
#pragma unroll
            for (int r = 0; r < 4; ++r) need = need || (pmax[r] > m_r[r] + 11.5f);
            if (__any(need)) {
                float tmax[4];
#pragma unroll
                for (int r = 0; r < 4; ++r) {
                    tmax[r] = pmax[r];
                    tmax[r] = fmaxf(tmax[r], __shfl_xor(tmax[r], 1, 64));
                    tmax[r] = fmaxf(tmax[r], __shfl_xor(tmax[r], 2, 64));
                    tmax[r] = fmaxf(tmax[r], __shfl_xor(tmax[r], 4, 64));
                    tmax[r] = fmaxf(tmax[r], __shfl_xor(tmax[r], 8, 64));
                }
                float a_r[4];
#pragma unroll
                for (int r = 0; r < 4; ++r) {
                    const float mnew = fmaxf(m_r[r], tmax[r]);
                    a_r[r] = exp2_fast(m_r[r] - mnew);
                    m_r[r] = mnew;
                    lacc[r] *= a_r[r];
                }
#pragma unroll
                for (int ct = 0; ct < 8; ++ct)
#pragma unroll
                    for (int r = 0; r < 4; ++r) Oacc[ct][r] *= a_r[r];
            }

            // P = exp2(S - m) -> LDS (per-wave, swizzled, HW cvt)
#pragma unroll
            for (int t = 0; t < 4; ++t)
#pragma unroll
                for (int r = 0; r < 4; ++r)
                    *(unsigned short*)(Pb + sw128((r0 + r) * 128 + (t * 16 + frow) * 2)) =
                        f2b_hw(exp2_fast(sc4[t][r] - m_r[r]));

            // PV + l-accumulate (ones column)
#pragma unroll
            for (int ks = 0; ks < 2; ++ks) {
                bf16x8 pf = ld8_off((const unsigned short*)Pb, sw128(frow * 128 + ks * 64 + g16));
                lacc = __builtin_amdgcn_mfma_f32_16x16x32_bf16(pf, ones, lacc, 0, 0, 0);
#pragma unroll
                for (int ct = 0; ct < 8; ++ct) {
                    bf16x8 vf = ld8_off(Vsm, sw128((ct * 16 + frow) * 128 + ks * 64 + g16));
                    Oacc[ct] = __builtin_amdgcn_mfma_f32_16x16x32_bf16(pf, vf, Oacc[ct], 0, 0, 0);
                }
            }

            __syncthreads();   // barrier B: all V reads done; K(kt+1) landed
            if (kt < qt) {
                const unsigned short* vt_g = vg + (kt + 1) * 64;
#pragma unroll
                for (int i = 0; i < 4; ++i)
                    gload_lds16(vt_g + voff[i], Vsm + i * 2048 + tid * 8);
            }
        }

        // epilogue: rcp multiply (l >= 1: diagonal contributes exp2(0))
        float rl[4];
#pragma unroll
        for (int r = 0; r < 4; ++r) rl[r] = __builtin_amdgcn_rcpf(lacc[r]);
#pragma unroll
        for (int ct = 0; ct < 8; ++ct) {
            const int d = ct * 16 + frow;
#pragma unroll
            for (int r = 0; r < 4; ++r) {
                const size_t row = (size_t)(q0 + r0 + r) * BB + bb;
                context[row * HH + nh * 128 + d] = f2b_hw(Oacc[ct][r] * rl[r]);
            }
        }
    }
}

extern "C" void kernel_launch(void* const* d_in, const int* in_sizes, int n_in,
                              void* d_out, int out_size, void* d_ws, size_t ws_size,
                              hipStream_t stream) {
    const float* hidden  = (const float*)d_in[0];
    // d_in[1] = attention_mask: deterministically causal (triu k=1) -> applied analytically
    const float* w_qkv   = (const float*)d_in[2];
    const float* b_qkv   = (const float*)d_in[3];
    const float* w_dense = (const float*)d_in[4];
    const float* b_dense = (const float*)d_in[5];
    float* out = (float*)d_out;

    // ws layout (bf16 elements), 96MB total:
    //  [mixed 48MB][hb 16MB -> context after GEMM1][wq 24MB -> vt after GEMM1][wd 8MB]
    unsigned short* mixed = (unsigned short*)d_ws;
    unsigned short* hb    = mixed + (size_t)MROWS * H3;
    unsigned short* wq    = hb + (size_t)MROWS * HH;
    unsigned short* wd    = wq + (size_t)H3 * HH;
    unsigned short* context = hb;   // alias: hb dead after GEMM1
    unsigned short* vtg     = wq;   // alias: wq dead after GEMM1 (16MB <= 24MB)

    dim3 blk(256);
    // fp32 -> bf16 pre-passes (memory-bound)
    cvt_f32_bf16<<<2048, blk, 0, stream>>>(hidden, hb, (MROWS * HH) / 4);
    cvt_f32_bf16<<<2048, blk, 0, stream>>>(w_qkv, wq, (H3 * HH) / 4);
    cvt_f32_bf16<<<1024, blk, 0, stream>>>(w_dense, wd, (HH * HH) / 4);

    // QKV projection: [4096,2048] x [6144,2048]^T -> mixed bf16 (Q pre-scaled)
    // BN=192, 80KB LDS, MINW=4 -> 2 blocks/CU (R21-measured 95us, 50% util)
    hipFuncSetAttribute(reinterpret_cast<const void*>(gemm_8ph<192, false, 4>),
                        hipFuncAttributeMaxDynamicSharedMemorySize, 81920);
    gemm_8ph<192, false, 4><<<dim3(H3 / 192, MROWS / 128), dim3(512), 81920, stream>>>(
        hb, wq, b_qkv, mixed, H3, HH);
    // V transpose pre-pass: mixed -> vtg [b*head][d][s]
    transpose_v<<<dim3(32, NHEAD, BB), blk, 0, stream>>>(mixed, vtg);
    // causal flash attention -> context bf16 (512 blocks, XCD remap, paired)
    attn_kernel<<<dim3(512), blk, 0, stream>>>(mixed, vtg, context);
    // dense projection: [4096,2048] x [2048,2048]^T -> out fp32
    // BN=256, 96KB LDS, MINW=2 (R19-proven; MINW=4 spilled NF=4 in R21)
    hipFuncSetAttribute(reinterpret_cast<const void*>(gemm_8ph<256, true, 2>),
                        hipFuncAttributeMaxDynamicSharedMemorySize, 98304);
    gemm_8ph<256, true, 2><<<dim3(HH / 256, MROWS / 128), dim3(512), 98304, stream>>>(
        context, wd, b_dense, out, HH, HH);
}